// Round 16
// baseline (4017.501 us; speedup 1.0000x reference)
//
#include <hip/hip_runtime.h>
#include <math.h>

#define BATCH 4096
#define NIN   4096
#define NOUT  4096

#define BM 128
#define BN 128
#define BK 32
#define NSTAGE (NIN / BK)        // 128
// R9-verified ACID ORDER (frozen): [512x8] k-panels, single ascending fmaf
// chain, fold every 16 stages, f32 epilogue. BASE on MFMA pipe (R13-verified).
// R16: 3 blocks/CU via smem 67584->53760 (half-Bout combine + unpadded Bs).

typedef __attribute__((ext_vector_type(8))) short bf16x8;
typedef __attribute__((ext_vector_type(8))) unsigned short u16x8;
typedef __attribute__((ext_vector_type(4))) float f32x4;

__device__ __forceinline__ float2 compute_terms(float xv) {
    float h  = (float)exp10(-(double)xv);
    float oh = 1e-14f / h;
    return make_float2(h * 0.1f, oh * 0.1f);
}
__device__ __forceinline__ unsigned short bf16_rne(float v) {
    unsigned int b = __float_as_uint(v);
    return (unsigned short)((b + 0x7FFFu + ((b >> 16) & 1u)) >> 16);
}
__device__ __forceinline__ float signf_of(float wv) {
    return (wv > 0.f) ? 1.f : ((wv < 0.f) ? -1.f : 0.f);
}
__device__ __forceinline__ unsigned short signbf16_of(float wv) {
    return (wv > 0.f) ? 0x3F80u : ((wv < 0.f) ? 0xBF80u : 0u);
}

// --- precompute A: acid f32 TRANSPOSED AaT[k][m] (LDS-tiled) + base bf16 Ab[m][k] ---
__global__ __launch_bounds__(256) void precompute_A(const float* __restrict__ x,
                                                    float* __restrict__ aaT,
                                                    unsigned short* __restrict__ ab) {
    __shared__ float tile[64][65];
    const int m0 = blockIdx.y * 64, k0 = blockIdx.x * 64;
    const int tid = threadIdx.x;
    #pragma unroll
    for (int it = 0; it < 4; ++it) {
        int idx = tid + it * 256;
        int row = idx >> 4, q = idx & 15;
        float4 xv = *(const float4*)(x + (size_t)(m0 + row) * NIN + k0 + q * 4);
        float2 t0 = compute_terms(xv.x), t1 = compute_terms(xv.y),
               t2 = compute_terms(xv.z), t3 = compute_terms(xv.w);
        *(ushort4*)(ab + (size_t)(m0 + row) * NIN + k0 + q * 4) =
            make_ushort4(bf16_rne(t0.y), bf16_rne(t1.y), bf16_rne(t2.y), bf16_rne(t3.y));
        tile[row][q * 4 + 0] = t0.x; tile[row][q * 4 + 1] = t1.x;
        tile[row][q * 4 + 2] = t2.x; tile[row][q * 4 + 3] = t3.x;
    }
    __syncthreads();
    #pragma unroll
    for (int it = 0; it < 4; ++it) {
        int idx = tid + it * 256;
        int krow = idx >> 4, q = idx & 15;
        float4 v = make_float4(tile[q * 4 + 0][krow], tile[q * 4 + 1][krow],
                               tile[q * 4 + 2][krow], tile[q * 4 + 3][krow]);
        *(float4*)(aaT + (size_t)(k0 + krow) * NIN + m0 + q * 4) = v;
    }
}

// --- precompute W: sign bf16 TRANSPOSED signT[n][k] (LDS-tiled) ---
__global__ __launch_bounds__(256) void precompute_signT(const float* __restrict__ w,
                                                        unsigned short* __restrict__ sT) {
    __shared__ unsigned short tile[64][68];
    const int k0 = blockIdx.y * 64, n0 = blockIdx.x * 64;
    const int tid = threadIdx.x;
    #pragma unroll
    for (int it = 0; it < 4; ++it) {
        int idx = tid + it * 256;
        int krow = idx >> 4, q = idx & 15;
        float4 wv = *(const float4*)(w + (size_t)(k0 + krow) * NOUT + n0 + q * 4);
        *(ushort4*)&tile[krow][q * 4] =
            make_ushort4(signbf16_of(wv.x), signbf16_of(wv.y), signbf16_of(wv.z), signbf16_of(wv.w));
    }
    __syncthreads();
    #pragma unroll
    for (int it = 0; it < 2; ++it) {
        int idx = tid + it * 256;
        int n = idx >> 3, kc = idx & 7;
        u16x8 v;
        #pragma unroll
        for (int j = 0; j < 8; ++j) v[j] = tile[kc * 8 + j][n];
        *(u16x8*)(sT + (size_t)(n0 + n) * NIN + k0 + kc * 8) = v;
    }
}

// LDS plan (53760 B -> 3 blocks/CU):
//   As_acid [32][132] f32 @0      (16896)  acid A [k][m]
//   Bs      [32][128] f32 @16896  (16384)  sign(W) f32 [k][n] (rows 512B: aligned, 2-way free)
//   baseA   [128][40] u16 @33280  (10240)  base A bf16 [m][k]
//   Bt      [128][40] u16 @43520  (10240)  sign bf16 [n][k]
//   Bout_h  [128][68] f32 @0      (34816)  HALF base result (post-loop alias; 2 passes)
#define OFF_BS 16896
#define OFF_BA 33280
#define OFF_BT 43520

__global__ __launch_bounds__(256, 3) void acid_gemm_hyb(const float* __restrict__ AaT,
                                                        const unsigned short* __restrict__ Ab,
                                                        const unsigned short* __restrict__ SignT,
                                                        const float* __restrict__ W,
                                                        float* __restrict__ out) {
    __shared__ __align__(16) char smem[53760];
    float*          As_acid = (float*)smem;
    float*          Bs      = (float*)(smem + OFF_BS);
    unsigned short* baseA   = (unsigned short*)(smem + OFF_BA);
    unsigned short* Bt      = (unsigned short*)(smem + OFF_BT);
    float*          BoutH   = (float*)smem;

    const int tid  = threadIdx.x;
    const int tx   = tid & 15;     // acid cols: tx*4..+3 and 64+tx*4..+3
    const int ty   = tid >> 4;     // acid rows ty*8..+7
    const int lane = tid & 63;
    const int wv   = tid >> 6;
    const int g    = lane >> 4;
    const int r16  = lane & 15;
    const int bm0  = blockIdx.y * BM;
    const int bn0  = blockIdx.x * BN;

    float ma[8][8] = {}, ca[8][8] = {};
    f32x4 acc[2][8] = {};

    float4 areg[4];      // AaT: k-row tid>>3, m-quads (tid&7)+8r
    u16x8  breg[2];      // Ab: rows (tid>>2)+64r, chunk tid&3
    float4 wreg[2][2];   // W: k rows (tid>>4)+16r, halves h*64, col-quad tid&15
    u16x8  btreg[2];     // SignT: rows (tid>>2)+64r, chunk tid&3

    #define ISSUE_LOADS(s)                                                         \
        {                                                                          \
            const int k0_ = (s) * BK;                                              \
            _Pragma("unroll")                                                      \
            for (int r = 0; r < 4; ++r)                                            \
                areg[r] = *(const float4*)(AaT +                                   \
                    (size_t)(k0_ + (tid >> 3)) * NIN + bm0 + ((tid & 7) + 8 * r) * 4);\
            _Pragma("unroll")                                                      \
            for (int r = 0; r < 2; ++r)                                            \
                breg[r] = *(const u16x8*)(Ab +                                     \
                    (size_t)(bm0 + (tid >> 2) + 64 * r) * NIN + k0_ + (tid & 3) * 8);\
            _Pragma("unroll")                                                      \
            for (int r = 0; r < 2; ++r)                                            \
                _Pragma("unroll")                                                  \
                for (int h = 0; h < 2; ++h)                                        \
                    wreg[r][h] = *(const float4*)(W +                              \
                        (size_t)(k0_ + (tid >> 4) + 16 * r) * NOUT + bn0 + h * 64 + (tid & 15) * 4);\
            _Pragma("unroll")                                                      \
            for (int r = 0; r < 2; ++r)                                            \
                btreg[r] = *(const u16x8*)(SignT +                                 \
                    (size_t)(bn0 + (tid >> 2) + 64 * r) * NIN + k0_ + (tid & 3) * 8);\
        }

    #define WRITE_LDS()                                                            \
        {                                                                          \
            _Pragma("unroll")                                                      \
            for (int r = 0; r < 4; ++r)                                            \
                *(float4*)&As_acid[(tid >> 3) * 132 + ((tid & 7) + 8 * r) * 4] = areg[r];\
            _Pragma("unroll")                                                      \
            for (int r = 0; r < 2; ++r)                                            \
                *(u16x8*)&baseA[((tid >> 2) + 64 * r) * 40 + (tid & 3) * 8] = breg[r];\
            _Pragma("unroll")                                                      \
            for (int r = 0; r < 2; ++r)                                            \
                _Pragma("unroll")                                                  \
                for (int h = 0; h < 2; ++h) {                                      \
                    float4 w_ = wreg[r][h];                                        \
                    *(float4*)&Bs[((tid >> 4) + 16 * r) * 128 + h * 64 + (tid & 15) * 4] = \
                        make_float4(signf_of(w_.x), signf_of(w_.y),                \
                                    signf_of(w_.z), signf_of(w_.w));               \
                }                                                                  \
            _Pragma("unroll")                                                      \
            for (int r = 0; r < 2; ++r)                                            \
                *(u16x8*)&Bt[((tid >> 2) + 64 * r) * 40 + (tid & 3) * 8] = btreg[r];\
        }

    ISSUE_LOADS(0);
    WRITE_LDS();
    __syncthreads();

    for (int s = 0; s < NSTAGE; ++s) {
        if (s + 1 < NSTAGE) ISSUE_LOADS(s + 1);   // T14: in flight across compute

        // ---- base GEMM on the matrix pipe ----
        {
            bf16x8 af0 = *(const bf16x8*)&baseA[(wv * 32 +      r16) * 40 + g * 8];
            bf16x8 af1 = *(const bf16x8*)&baseA[(wv * 32 + 16 + r16) * 40 + g * 8];
            #pragma unroll
            for (int tc = 0; tc < 8; ++tc) {
                bf16x8 bf = *(const bf16x8*)&Bt[(tc * 16 + r16) * 40 + g * 8];
                acc[0][tc] = __builtin_amdgcn_mfma_f32_16x16x32_bf16(af0, bf, acc[0][tc], 0, 0, 0);
                acc[1][tc] = __builtin_amdgcn_mfma_f32_16x16x32_bf16(af1, bf, acc[1][tc], 0, 0, 0);
            }
        }

        // ---- acid chain: 32 ascending k, bit-identical order to R9/R15 ----
        #pragma unroll 4
        for (int k = 0; k < BK; ++k) {
            const float4 pa = *(const float4*)&As_acid[k * 132 + ty * 8];
            const float4 pb = *(const float4*)&As_acid[k * 132 + ty * 8 + 4];
            const float4 s0 = *(const float4*)&Bs[k * 128 + tx * 4];
            const float4 s1 = *(const float4*)&Bs[k * 128 + 64 + tx * 4];
            const float av[8] = {pa.x, pa.y, pa.z, pa.w, pb.x, pb.y, pb.z, pb.w};
            const float sn[8] = {s0.x, s0.y, s0.z, s0.w, s1.x, s1.y, s1.z, s1.w};
            #pragma unroll
            for (int m = 0; m < 8; ++m)
                #pragma unroll
                for (int n = 0; n < 8; ++n)
                    ca[m][n] = fmaf(av[m], sn[n], ca[m][n]);
        }

        if (((s + 1) & 15) == 0) {     // panel fold every 512 k
            #pragma unroll
            for (int m = 0; m < 8; ++m)
                #pragma unroll
                for (int n = 0; n < 8; ++n) {
                    ma[m][n] += ca[m][n]; ca[m][n] = 0.f;
                }
        }

        __syncthreads();
        if (s + 1 < NSTAGE) WRITE_LDS();
        __syncthreads();
    }

    // ---- combine base frags + epilogue, in two column halves ----
    #pragma unroll
    for (int hh = 0; hh < 2; ++hh) {
        // write half hh's frags (cols hh*64..+63) into BoutH
        #pragma unroll
        for (int tr = 0; tr < 2; ++tr)
            #pragma unroll
            for (int tc = 0; tc < 4; ++tc)
                #pragma unroll
                for (int rr = 0; rr < 4; ++rr)
                    BoutH[(wv * 32 + tr * 16 + g * 4 + rr) * 68 + tc * 16 + r16] =
                        acc[tr][hh * 4 + tc][rr];
        __syncthreads();
        #pragma unroll
        for (int m = 0; m < 8; ++m) {
            int row = ty * 8 + m;
            const float4 bv = *(const float4*)&BoutH[row * 68 + tx * 4];
            const float bb[4] = {bv.x, bv.y, bv.z, bv.w};
            #pragma unroll
            for (int n = 0; n < 4; ++n) {
                float r    = ma[m][hh * 4 + n] - bb[n];
                float conc = fabsf(r) / 409.6f;
                float hc   = (r < 0.f) ? (1e-14f / conc) : conc;
                float ph   = (-logf(hc)) / 2.302585092994046f;
                out[(size_t)(bm0 + row) * NOUT + bn0 + hh * 64 + tx * 4 + n] = ph;
            }
        }
        __syncthreads();
    }
    #undef ISSUE_LOADS
    #undef WRITE_LDS
}

// Fallback (ws too small): R9's proven all-VALU kernel, on-the-fly terms.
__global__ __launch_bounds__(256, 2) void acid_gemm_fly(const float* __restrict__ X,
                                                        const float* __restrict__ W,
                                                        float* __restrict__ out) {
    __shared__ float2 Asf[BK][128 + 2];
    __shared__ float  Bsf[BK][64];
    const int tid = threadIdx.x;
    const int tx = tid & 15, ty = tid >> 4;
    const int bm0 = blockIdx.y * 128, bn0 = blockIdx.x * 64;
    float ma[8][4] = {}, mb[8][4] = {}, ca[8][4] = {}, cb[8][4] = {};
    for (int s = 0; s < NSTAGE; ++s) {
        const int k0 = s * BK;
        for (int idx = tid; idx < 128 * BK; idx += 256) {
            int m = idx >> 5, k = idx & 31;
            Asf[k][m] = compute_terms(X[(size_t)(bm0 + m) * NIN + k0 + k]);
        }
        for (int idx = tid; idx < BK * 64; idx += 256) {
            int k = idx >> 6, c = idx & 63;
            Bsf[k][c] = signf_of(W[(size_t)(k0 + k) * NOUT + bn0 + c]);
        }
        __syncthreads();
        #pragma unroll 4
        for (int k = 0; k < BK; ++k) {
            float2 av[8]; float sv[4];
            #pragma unroll
            for (int m = 0; m < 8; ++m) av[m] = Asf[k][ty * 8 + m];
            #pragma unroll
            for (int n = 0; n < 4; ++n) sv[n] = Bsf[k][tx * 4 + n];
            #pragma unroll
            for (int m = 0; m < 8; ++m)
                #pragma unroll
                for (int n = 0; n < 4; ++n) {
                    ca[m][n] = fmaf(av[m].x, sv[n], ca[m][n]);
                    cb[m][n] = fmaf(av[m].y, sv[n], cb[m][n]);
                }
        }
        if (((s + 1) & 15) == 0) {
            #pragma unroll
            for (int m = 0; m < 8; ++m)
                #pragma unroll
                for (int n = 0; n < 4; ++n) {
                    ma[m][n] += ca[m][n]; ca[m][n] = 0.f;
                    mb[m][n] += cb[m][n]; cb[m][n] = 0.f;
                }
        }
        __syncthreads();
    }
    #pragma unroll
    for (int m = 0; m < 8; ++m) {
        int row = bm0 + ty * 8 + m;
        #pragma unroll
        for (int n = 0; n < 4; ++n) {
            int col = bn0 + tx * 4 + n;
            float r = ma[m][n] - mb[m][n];
            float conc = fabsf(r) / 409.6f;
            float hc = (r < 0.f) ? (1e-14f / conc) : conc;
            out[(size_t)row * NOUT + col] = (-logf(hc)) / 2.302585092994046f;
        }
    }
}

extern "C" void kernel_launch(void* const* d_in, const int* in_sizes, int n_in,
                              void* d_out, int out_size, void* d_ws, size_t ws_size,
                              hipStream_t stream) {
    const float* x = (const float*)d_in[0];
    const float* w = (const float*)d_in[1];
    float* out = (float*)d_out;

    const size_t nElem  = (size_t)BATCH * NIN;
    const size_t needWs = nElem * 4 + nElem * 2 + nElem * 2;   // AaT + Ab + signT = 134.2 MB
    dim3 grid(NOUT / BN, BATCH / BM);

    if (ws_size >= needWs) {
        float*          aaT   = (float*)d_ws;
        unsigned short* ab    = (unsigned short*)((char*)d_ws + nElem * 4);
        unsigned short* signT = (unsigned short*)((char*)d_ws + nElem * 6);
        precompute_A    <<<dim3(64, 64), 256, 0, stream>>>(x, aaT, ab);
        precompute_signT<<<dim3(64, 64), 256, 0, stream>>>(w, signT);
        acid_gemm_hyb   <<<grid, dim3(256), 0, stream>>>(aaT, ab, signT, w, out);
    } else {
        acid_gemm_fly<<<dim3(NOUT / 64, BATCH / 128), dim3(256), 0, stream>>>(x, w, out);
    }
}

// Round 17
// 2387.124 us; speedup vs baseline: 1.6830x; 1.6830x over previous
//
#include <hip/hip_runtime.h>
#include <math.h>

#define BATCH 4096
#define NIN   4096
#define NOUT  4096

#define BM 128
#define BN 128
#define BK 32
#define NSTAGE (NIN / BK)        // 128
// R9-verified ACID ORDER (frozen): [512x8] k-panels, single ascending fmaf
// chain, fold every 16 stages, f32 epilogue. BASE on MFMA pipe (R13-verified).
// R17: acid B-signs as bf16 in LDS (b64 reads + bit-exact <<16 unpack);
// LDS 53760->45568 -> 3 blocks/CU. VGPR law (R12/R16): never force min-waves
// below the accumulator footprint -- keep launch_bounds(256,2).

typedef __attribute__((ext_vector_type(8))) short bf16x8;
typedef __attribute__((ext_vector_type(8))) unsigned short u16x8;
typedef __attribute__((ext_vector_type(4))) float f32x4;

__device__ __forceinline__ float2 compute_terms(float xv) {
    float h  = (float)exp10(-(double)xv);
    float oh = 1e-14f / h;
    return make_float2(h * 0.1f, oh * 0.1f);
}
__device__ __forceinline__ unsigned short bf16_rne(float v) {
    unsigned int b = __float_as_uint(v);
    return (unsigned short)((b + 0x7FFFu + ((b >> 16) & 1u)) >> 16);
}
__device__ __forceinline__ float signf_of(float wv) {
    return (wv > 0.f) ? 1.f : ((wv < 0.f) ? -1.f : 0.f);
}
__device__ __forceinline__ unsigned int signu16_of(float wv) {
    return (wv > 0.f) ? 0x3F80u : ((wv < 0.f) ? 0xBF80u : 0u);
}
__device__ __forceinline__ unsigned short signbf16_of(float wv) {
    return (wv > 0.f) ? 0x3F80u : ((wv < 0.f) ? 0xBF80u : 0u);
}

// --- precompute A: acid f32 TRANSPOSED AaT[k][m] (LDS-tiled) + base bf16 Ab[m][k] ---
__global__ __launch_bounds__(256) void precompute_A(const float* __restrict__ x,
                                                    float* __restrict__ aaT,
                                                    unsigned short* __restrict__ ab) {
    __shared__ float tile[64][65];
    const int m0 = blockIdx.y * 64, k0 = blockIdx.x * 64;
    const int tid = threadIdx.x;
    #pragma unroll
    for (int it = 0; it < 4; ++it) {
        int idx = tid + it * 256;
        int row = idx >> 4, q = idx & 15;
        float4 xv = *(const float4*)(x + (size_t)(m0 + row) * NIN + k0 + q * 4);
        float2 t0 = compute_terms(xv.x), t1 = compute_terms(xv.y),
               t2 = compute_terms(xv.z), t3 = compute_terms(xv.w);
        *(ushort4*)(ab + (size_t)(m0 + row) * NIN + k0 + q * 4) =
            make_ushort4(bf16_rne(t0.y), bf16_rne(t1.y), bf16_rne(t2.y), bf16_rne(t3.y));
        tile[row][q * 4 + 0] = t0.x; tile[row][q * 4 + 1] = t1.x;
        tile[row][q * 4 + 2] = t2.x; tile[row][q * 4 + 3] = t3.x;
    }
    __syncthreads();
    #pragma unroll
    for (int it = 0; it < 4; ++it) {
        int idx = tid + it * 256;
        int krow = idx >> 4, q = idx & 15;
        float4 v = make_float4(tile[q * 4 + 0][krow], tile[q * 4 + 1][krow],
                               tile[q * 4 + 2][krow], tile[q * 4 + 3][krow]);
        *(float4*)(aaT + (size_t)(k0 + krow) * NIN + m0 + q * 4) = v;
    }
}

// --- precompute W: sign bf16 TRANSPOSED signT[n][k] (LDS-tiled) ---
__global__ __launch_bounds__(256) void precompute_signT(const float* __restrict__ w,
                                                        unsigned short* __restrict__ sT) {
    __shared__ unsigned short tile[64][68];
    const int k0 = blockIdx.y * 64, n0 = blockIdx.x * 64;
    const int tid = threadIdx.x;
    #pragma unroll
    for (int it = 0; it < 4; ++it) {
        int idx = tid + it * 256;
        int krow = idx >> 4, q = idx & 15;
        float4 wv = *(const float4*)(w + (size_t)(k0 + krow) * NOUT + n0 + q * 4);
        *(ushort4*)&tile[krow][q * 4] =
            make_ushort4(signbf16_of(wv.x), signbf16_of(wv.y), signbf16_of(wv.z), signbf16_of(wv.w));
    }
    __syncthreads();
    #pragma unroll
    for (int it = 0; it < 2; ++it) {
        int idx = tid + it * 256;
        int n = idx >> 3, kc = idx & 7;
        u16x8 v;
        #pragma unroll
        for (int j = 0; j < 8; ++j) v[j] = tile[kc * 8 + j][n];
        *(u16x8*)(sT + (size_t)(n0 + n) * NIN + k0 + kc * 8) = v;
    }
}

// LDS plan (45568 B -> 3 blocks/CU):
//   As_acid [32][132] f32 @0      (16896)  acid A [k][m]
//   signKN  [32][128] u16 @16896  (8192)   sign(W) bf16 [k][n] (rows 256B)
//   baseA   [128][40] u16 @25088  (10240)  base A bf16 [m][k]
//   Bt      [128][40] u16 @35328  (10240)  sign bf16 [n][k]
//   BoutH   [128][68] f32 @0      (34816)  HALF base result (post-loop alias)
#define OFF_SK 16896
#define OFF_BA 25088
#define OFF_BT 35328

__global__ __launch_bounds__(256, 2) void acid_gemm_hyb(const float* __restrict__ AaT,
                                                        const unsigned short* __restrict__ Ab,
                                                        const unsigned short* __restrict__ SignT,
                                                        const float* __restrict__ W,
                                                        float* __restrict__ out) {
    __shared__ __align__(16) char smem[45568];
    float*          As_acid = (float*)smem;
    unsigned short* signKN  = (unsigned short*)(smem + OFF_SK);
    unsigned short* baseA   = (unsigned short*)(smem + OFF_BA);
    unsigned short* Bt      = (unsigned short*)(smem + OFF_BT);
    float*          BoutH   = (float*)smem;

    const int tid  = threadIdx.x;
    const int tx   = tid & 15;     // acid cols: tx*4..+3 and 64+tx*4..+3
    const int ty   = tid >> 4;     // acid rows ty*8..+7
    const int lane = tid & 63;
    const int wv   = tid >> 6;
    const int g    = lane >> 4;
    const int r16  = lane & 15;
    const int bm0  = blockIdx.y * BM;
    const int bn0  = blockIdx.x * BN;

    float ma[8][8] = {}, ca[8][8] = {};
    f32x4 acc[2][8] = {};

    float4 areg[4];      // AaT: k-row tid>>3, m-quads (tid&7)+8r
    u16x8  breg[2];      // Ab: rows (tid>>2)+64r, chunk tid&3
    float4 wreg[2][2];   // W: k rows (tid>>4)+16r, halves h*64, col-quad tid&15
    u16x8  btreg[2];     // SignT: rows (tid>>2)+64r, chunk tid&3

    #define ISSUE_LOADS(s)                                                         \
        {                                                                          \
            const int k0_ = (s) * BK;                                              \
            _Pragma("unroll")                                                      \
            for (int r = 0; r < 4; ++r)                                            \
                areg[r] = *(const float4*)(AaT +                                   \
                    (size_t)(k0_ + (tid >> 3)) * NIN + bm0 + ((tid & 7) + 8 * r) * 4);\
            _Pragma("unroll")                                                      \
            for (int r = 0; r < 2; ++r)                                            \
                breg[r] = *(const u16x8*)(Ab +                                     \
                    (size_t)(bm0 + (tid >> 2) + 64 * r) * NIN + k0_ + (tid & 3) * 8);\
            _Pragma("unroll")                                                      \
            for (int r = 0; r < 2; ++r)                                            \
                _Pragma("unroll")                                                  \
                for (int h = 0; h < 2; ++h)                                        \
                    wreg[r][h] = *(const float4*)(W +                              \
                        (size_t)(k0_ + (tid >> 4) + 16 * r) * NOUT + bn0 + h * 64 + (tid & 15) * 4);\
            _Pragma("unroll")                                                      \
            for (int r = 0; r < 2; ++r)                                            \
                btreg[r] = *(const u16x8*)(SignT +                                 \
                    (size_t)(bn0 + (tid >> 2) + 64 * r) * NIN + k0_ + (tid & 3) * 8);\
        }

    #define WRITE_LDS()                                                            \
        {                                                                          \
            _Pragma("unroll")                                                      \
            for (int r = 0; r < 4; ++r)                                            \
                *(float4*)&As_acid[(tid >> 3) * 132 + ((tid & 7) + 8 * r) * 4] = areg[r];\
            _Pragma("unroll")                                                      \
            for (int r = 0; r < 2; ++r)                                            \
                *(u16x8*)&baseA[((tid >> 2) + 64 * r) * 40 + (tid & 3) * 8] = breg[r];\
            _Pragma("unroll")                                                      \
            for (int r = 0; r < 2; ++r)                                            \
                _Pragma("unroll")                                                  \
                for (int h = 0; h < 2; ++h) {                                      \
                    float4 w_ = wreg[r][h];                                        \
                    uint2 pk;                                                      \
                    pk.x = signu16_of(w_.x) | (signu16_of(w_.y) << 16);            \
                    pk.y = signu16_of(w_.z) | (signu16_of(w_.w) << 16);            \
                    *(uint2*)&signKN[((tid >> 4) + 16 * r) * 128 + h * 64 + (tid & 15) * 4] = pk;\
                }                                                                  \
            _Pragma("unroll")                                                      \
            for (int r = 0; r < 2; ++r)                                            \
                *(u16x8*)&Bt[((tid >> 2) + 64 * r) * 40 + (tid & 3) * 8] = btreg[r];\
        }

    ISSUE_LOADS(0);
    WRITE_LDS();
    __syncthreads();

    for (int s = 0; s < NSTAGE; ++s) {
        if (s + 1 < NSTAGE) ISSUE_LOADS(s + 1);   // T14: in flight across compute

        // ---- base GEMM on the matrix pipe ----
        {
            bf16x8 af0 = *(const bf16x8*)&baseA[(wv * 32 +      r16) * 40 + g * 8];
            bf16x8 af1 = *(const bf16x8*)&baseA[(wv * 32 + 16 + r16) * 40 + g * 8];
            #pragma unroll
            for (int tc = 0; tc < 8; ++tc) {
                bf16x8 bf = *(const bf16x8*)&Bt[(tc * 16 + r16) * 40 + g * 8];
                acc[0][tc] = __builtin_amdgcn_mfma_f32_16x16x32_bf16(af0, bf, acc[0][tc], 0, 0, 0);
                acc[1][tc] = __builtin_amdgcn_mfma_f32_16x16x32_bf16(af1, bf, acc[1][tc], 0, 0, 0);
            }
        }

        // ---- acid chain: 32 ascending k, bit-identical order to R9/R15 ----
        // signs read as bf16 pairs (b64) and expanded bit-exactly:
        // 0x3F80<<16 = 1.0f, 0xBF80<<16 = -1.0f, 0 = 0.0f
        #pragma unroll 4
        for (int k = 0; k < BK; ++k) {
            const float4 pa = *(const float4*)&As_acid[k * 132 + ty * 8];
            const float4 pb = *(const float4*)&As_acid[k * 132 + ty * 8 + 4];
            const uint2  u0 = *(const uint2*)&signKN[k * 128 + tx * 4];
            const uint2  u1 = *(const uint2*)&signKN[k * 128 + 64 + tx * 4];
            const float av[8] = {pa.x, pa.y, pa.z, pa.w, pb.x, pb.y, pb.z, pb.w};
            const float sn[8] = {
                __uint_as_float(u0.x << 16), __uint_as_float(u0.x & 0xFFFF0000u),
                __uint_as_float(u0.y << 16), __uint_as_float(u0.y & 0xFFFF0000u),
                __uint_as_float(u1.x << 16), __uint_as_float(u1.x & 0xFFFF0000u),
                __uint_as_float(u1.y << 16), __uint_as_float(u1.y & 0xFFFF0000u)};
            #pragma unroll
            for (int m = 0; m < 8; ++m)
                #pragma unroll
                for (int n = 0; n < 8; ++n)
                    ca[m][n] = fmaf(av[m], sn[n], ca[m][n]);
        }

        if (((s + 1) & 15) == 0) {     // panel fold every 512 k
            #pragma unroll
            for (int m = 0; m < 8; ++m)
                #pragma unroll
                for (int n = 0; n < 8; ++n) {
                    ma[m][n] += ca[m][n]; ca[m][n] = 0.f;
                }
        }

        __syncthreads();
        if (s + 1 < NSTAGE) WRITE_LDS();
        __syncthreads();
    }

    // ---- combine base frags + epilogue, in two column halves ----
    #pragma unroll
    for (int hh = 0; hh < 2; ++hh) {
        #pragma unroll
        for (int tr = 0; tr < 2; ++tr)
            #pragma unroll
            for (int tc = 0; tc < 4; ++tc)
                #pragma unroll
                for (int rr = 0; rr < 4; ++rr)
                    BoutH[(wv * 32 + tr * 16 + g * 4 + rr) * 68 + tc * 16 + r16] =
                        acc[tr][hh * 4 + tc][rr];
        __syncthreads();
        #pragma unroll
        for (int m = 0; m < 8; ++m) {
            int row = ty * 8 + m;
            const float4 bv = *(const float4*)&BoutH[row * 68 + tx * 4];
            const float bb[4] = {bv.x, bv.y, bv.z, bv.w};
            #pragma unroll
            for (int n = 0; n < 4; ++n) {
                float r    = ma[m][hh * 4 + n] - bb[n];
                float conc = fabsf(r) / 409.6f;
                float hc   = (r < 0.f) ? (1e-14f / conc) : conc;
                float ph   = (-logf(hc)) / 2.302585092994046f;
                out[(size_t)(bm0 + row) * NOUT + bn0 + hh * 64 + tx * 4 + n] = ph;
            }
        }
        __syncthreads();
    }
    #undef ISSUE_LOADS
    #undef WRITE_LDS
}

// Fallback (ws too small): R9's proven all-VALU kernel, on-the-fly terms.
__global__ __launch_bounds__(256, 2) void acid_gemm_fly(const float* __restrict__ X,
                                                        const float* __restrict__ W,
                                                        float* __restrict__ out) {
    __shared__ float2 Asf[BK][128 + 2];
    __shared__ float  Bsf[BK][64];
    const int tid = threadIdx.x;
    const int tx = tid & 15, ty = tid >> 4;
    const int bm0 = blockIdx.y * 128, bn0 = blockIdx.x * 64;
    float ma[8][4] = {}, mb[8][4] = {}, ca[8][4] = {}, cb[8][4] = {};
    for (int s = 0; s < NSTAGE; ++s) {
        const int k0 = s * BK;
        for (int idx = tid; idx < 128 * BK; idx += 256) {
            int m = idx >> 5, k = idx & 31;
            Asf[k][m] = compute_terms(X[(size_t)(bm0 + m) * NIN + k0 + k]);
        }
        for (int idx = tid; idx < BK * 64; idx += 256) {
            int k = idx >> 6, c = idx & 63;
            Bsf[k][c] = signf_of(W[(size_t)(k0 + k) * NOUT + bn0 + c]);
        }
        __syncthreads();
        #pragma unroll 4
        for (int k = 0; k < BK; ++k) {
            float2 av[8]; float sv[4];
            #pragma unroll
            for (int m = 0; m < 8; ++m) av[m] = Asf[k][ty * 8 + m];
            #pragma unroll
            for (int n = 0; n < 4; ++n) sv[n] = Bsf[k][tx * 4 + n];
            #pragma unroll
            for (int m = 0; m < 8; ++m)
                #pragma unroll
                for (int n = 0; n < 4; ++n) {
                    ca[m][n] = fmaf(av[m].x, sv[n], ca[m][n]);
                    cb[m][n] = fmaf(av[m].y, sv[n], cb[m][n]);
                }
        }
        if (((s + 1) & 15) == 0) {
            #pragma unroll
            for (int m = 0; m < 8; ++m)
                #pragma unroll
                for (int n = 0; n < 4; ++n) {
                    ma[m][n] += ca[m][n]; ca[m][n] = 0.f;
                    mb[m][n] += cb[m][n]; cb[m][n] = 0.f;
                }
        }
        __syncthreads();
    }
    #pragma unroll
    for (int m = 0; m < 8; ++m) {
        int row = bm0 + ty * 8 + m;
        #pragma unroll
        for (int n = 0; n < 4; ++n) {
            int col = bn0 + tx * 4 + n;
            float r = ma[m][n] - mb[m][n];
            float conc = fabsf(r) / 409.6f;
            float hc = (r < 0.f) ? (1e-14f / conc) : conc;
            out[(size_t)row * NOUT + col] = (-logf(hc)) / 2.302585092994046f;
        }
    }
}

extern "C" void kernel_launch(void* const* d_in, const int* in_sizes, int n_in,
                              void* d_out, int out_size, void* d_ws, size_t ws_size,
                              hipStream_t stream) {
    const float* x = (const float*)d_in[0];
    const float* w = (const float*)d_in[1];
    float* out = (float*)d_out;

    const size_t nElem  = (size_t)BATCH * NIN;
    const size_t needWs = nElem * 4 + nElem * 2 + nElem * 2;   // AaT + Ab + signT = 134.2 MB
    dim3 grid(NOUT / BN, BATCH / BM);

    if (ws_size >= needWs) {
        float*          aaT   = (float*)d_ws;
        unsigned short* ab    = (unsigned short*)((char*)d_ws + nElem * 4);
        unsigned short* signT = (unsigned short*)((char*)d_ws + nElem * 6);
        precompute_A    <<<dim3(64, 64), 256, 0, stream>>>(x, aaT, ab);
        precompute_signT<<<dim3(64, 64), 256, 0, stream>>>(w, signT);
        acid_gemm_hyb   <<<grid, dim3(256), 0, stream>>>(aaT, ab, signT, w, out);
    } else {
        acid_gemm_fly<<<dim3(NOUT / 64, BATCH / 128), dim3(256), 0, stream>>>(x, w, out);
    }
}

// Round 18
// 2193.059 us; speedup vs baseline: 1.8319x; 1.0885x over previous
//
#include <hip/hip_runtime.h>
#include <math.h>

#define BATCH 4096
#define NIN   4096
#define NOUT  4096

#define BM 128
#define BN 128
#define BK 32
#define NSTAGE (NIN / BK)        // 128
// R9-verified ACID ORDER (frozen): [512x8] k-panels, single ascending fmaf
// chain, fold every 16 stages, f32 epilogue. BASE on MFMA pipe (R13-verified).
// R18: full LDS double-buffer, ONE barrier/stage; baseA dropped from LDS
// (MFMA A-frag direct from global, L2/L3-resident); Bt compact [128][32]
// with 16B-chunk XOR swizzle. Registers: WRITE-then-ISSUE reuses the same
// staging regs (no doubling; R16 law: no spills allowed).

typedef __attribute__((ext_vector_type(8))) short bf16x8;
typedef __attribute__((ext_vector_type(8))) unsigned short u16x8;
typedef __attribute__((ext_vector_type(4))) float f32x4;

__device__ __forceinline__ float2 compute_terms(float xv) {
    float h  = (float)exp10(-(double)xv);
    float oh = 1e-14f / h;
    return make_float2(h * 0.1f, oh * 0.1f);
}
__device__ __forceinline__ unsigned short bf16_rne(float v) {
    unsigned int b = __float_as_uint(v);
    return (unsigned short)((b + 0x7FFFu + ((b >> 16) & 1u)) >> 16);
}
__device__ __forceinline__ float signf_of(float wv) {
    return (wv > 0.f) ? 1.f : ((wv < 0.f) ? -1.f : 0.f);
}
__device__ __forceinline__ unsigned short signbf16_of(float wv) {
    return (wv > 0.f) ? 0x3F80u : ((wv < 0.f) ? 0xBF80u : 0u);
}

// --- precompute A: acid f32 TRANSPOSED AaT[k][m] (LDS-tiled) + base bf16 Ab[m][k] ---
__global__ __launch_bounds__(256) void precompute_A(const float* __restrict__ x,
                                                    float* __restrict__ aaT,
                                                    unsigned short* __restrict__ ab) {
    __shared__ float tile[64][65];
    const int m0 = blockIdx.y * 64, k0 = blockIdx.x * 64;
    const int tid = threadIdx.x;
    #pragma unroll
    for (int it = 0; it < 4; ++it) {
        int idx = tid + it * 256;
        int row = idx >> 4, q = idx & 15;
        float4 xv = *(const float4*)(x + (size_t)(m0 + row) * NIN + k0 + q * 4);
        float2 t0 = compute_terms(xv.x), t1 = compute_terms(xv.y),
               t2 = compute_terms(xv.z), t3 = compute_terms(xv.w);
        *(ushort4*)(ab + (size_t)(m0 + row) * NIN + k0 + q * 4) =
            make_ushort4(bf16_rne(t0.y), bf16_rne(t1.y), bf16_rne(t2.y), bf16_rne(t3.y));
        tile[row][q * 4 + 0] = t0.x; tile[row][q * 4 + 1] = t1.x;
        tile[row][q * 4 + 2] = t2.x; tile[row][q * 4 + 3] = t3.x;
    }
    __syncthreads();
    #pragma unroll
    for (int it = 0; it < 4; ++it) {
        int idx = tid + it * 256;
        int krow = idx >> 4, q = idx & 15;
        float4 v = make_float4(tile[q * 4 + 0][krow], tile[q * 4 + 1][krow],
                               tile[q * 4 + 2][krow], tile[q * 4 + 3][krow]);
        *(float4*)(aaT + (size_t)(k0 + krow) * NIN + m0 + q * 4) = v;
    }
}

// --- precompute W: sign bf16 TRANSPOSED signT[n][k] (LDS-tiled) ---
__global__ __launch_bounds__(256) void precompute_signT(const float* __restrict__ w,
                                                        unsigned short* __restrict__ sT) {
    __shared__ unsigned short tile[64][68];
    const int k0 = blockIdx.y * 64, n0 = blockIdx.x * 64;
    const int tid = threadIdx.x;
    #pragma unroll
    for (int it = 0; it < 4; ++it) {
        int idx = tid + it * 256;
        int krow = idx >> 4, q = idx & 15;
        float4 wv = *(const float4*)(w + (size_t)(k0 + krow) * NOUT + n0 + q * 4);
        *(ushort4*)&tile[krow][q * 4] =
            make_ushort4(signbf16_of(wv.x), signbf16_of(wv.y), signbf16_of(wv.z), signbf16_of(wv.w));
    }
    __syncthreads();
    #pragma unroll
    for (int it = 0; it < 2; ++it) {
        int idx = tid + it * 256;
        int n = idx >> 3, kc = idx & 7;
        u16x8 v;
        #pragma unroll
        for (int j = 0; j < 8; ++j) v[j] = tile[kc * 8 + j][n];
        *(u16x8*)(sT + (size_t)(n0 + n) * NIN + k0 + kc * 8) = v;
    }
}

// LDS (81920 B = exactly 2 blocks/CU of 160 KiB), all double-buffered:
//   As0 @0      As1 @16384   [32][128] f32 acid A [k][m]
//   Bs0 @32768  Bs1 @49152   [32][128] f32 sign(W) [k][n]
//   Bt0 @65536  Bt1 @73728   [128][32] u16 sign bf16 [n][k], 16B-chunk XOR swizzle
//   BoutH [128][68] f32 @0   (34816) post-loop alias over As0/As1
#define LDS_AS0 0
#define LDS_AS1 16384
#define LDS_BS0 32768
#define LDS_BS1 49152
#define LDS_BT0 65536
#define LDS_BT1 73728

__global__ __launch_bounds__(256, 2) void acid_gemm_hyb(const float* __restrict__ AaT,
                                                        const unsigned short* __restrict__ Ab,
                                                        const unsigned short* __restrict__ SignT,
                                                        const float* __restrict__ W,
                                                        float* __restrict__ out) {
    __shared__ __align__(16) char smem[81920];
    float*          As0 = (float*)(smem + LDS_AS0);
    float*          As1 = (float*)(smem + LDS_AS1);
    float*          Bs0 = (float*)(smem + LDS_BS0);
    float*          Bs1 = (float*)(smem + LDS_BS1);
    unsigned short* Bt0 = (unsigned short*)(smem + LDS_BT0);
    unsigned short* Bt1 = (unsigned short*)(smem + LDS_BT1);
    float*          BoutH = (float*)smem;

    const int tid  = threadIdx.x;
    const int tx   = tid & 15;     // acid cols tx*4..+3 and 64+tx*4..+3
    const int ty   = tid >> 4;     // acid rows ty*8..+7
    const int lane = tid & 63;
    const int wv   = tid >> 6;
    const int g    = lane >> 4;    // MFMA k-group 0..3
    const int r16  = lane & 15;
    const int bm0  = blockIdx.y * BM;
    const int bn0  = blockIdx.x * BN;

    float ma[8][8] = {}, ca[8][8] = {};
    f32x4 acc[2][8] = {};

    float4 areg[4];      // AaT: k-row tid>>3, m-quads (tid&7)+8r
    float4 wreg[2][2];   // W: k rows (tid>>4)+16r, halves h*64, col-quad tid&15
    u16x8  btreg[2];     // SignT: row tid>>1, chunks (tid&1)*2+j

    #define ISSUE_LOADS(s)                                                          \
        {                                                                           \
            const int k0_ = (s) * BK;                                               \
            _Pragma("unroll")                                                       \
            for (int r = 0; r < 4; ++r)                                             \
                areg[r] = *(const float4*)(AaT +                                    \
                    (size_t)(k0_ + (tid >> 3)) * NIN + bm0 + ((tid & 7) + 8 * r) * 4);\
            _Pragma("unroll")                                                       \
            for (int r = 0; r < 2; ++r)                                             \
                _Pragma("unroll")                                                   \
                for (int h = 0; h < 2; ++h)                                         \
                    wreg[r][h] = *(const float4*)(W +                               \
                        (size_t)(k0_ + (tid >> 4) + 16 * r) * NOUT + bn0 + h * 64 + (tid & 15) * 4);\
            _Pragma("unroll")                                                       \
            for (int j = 0; j < 2; ++j)                                             \
                btreg[j] = *(const u16x8*)(SignT +                                  \
                    (size_t)(bn0 + (tid >> 1)) * NIN + k0_ + ((tid & 1) * 2 + j) * 8);\
        }

    #define WRITE_LDS(asp, bsp, btp)                                                \
        {                                                                           \
            _Pragma("unroll")                                                       \
            for (int r = 0; r < 4; ++r)                                             \
                *(float4*)&(asp)[(tid >> 3) * 128 + ((tid & 7) + 8 * r) * 4] = areg[r];\
            _Pragma("unroll")                                                       \
            for (int r = 0; r < 2; ++r)                                             \
                _Pragma("unroll")                                                   \
                for (int h = 0; h < 2; ++h) {                                       \
                    float4 w_ = wreg[r][h];                                         \
                    *(float4*)&(bsp)[((tid >> 4) + 16 * r) * 128 + h * 64 + (tid & 15) * 4] = \
                        make_float4(signf_of(w_.x), signf_of(w_.y),                 \
                                    signf_of(w_.z), signf_of(w_.w));                \
                }                                                                   \
            {                                                                       \
                int row_ = tid >> 1;                                                \
                _Pragma("unroll")                                                   \
                for (int j = 0; j < 2; ++j) {                                       \
                    int c_ = (tid & 1) * 2 + j;                                     \
                    int cs_ = c_ ^ (row_ & 3);                                      \
                    *(u16x8*)&(btp)[row_ * 32 + cs_ * 8] = btreg[j];                \
                }                                                                   \
            }                                                                       \
        }

    // one full stage: WRITE(s+1)->next bufs, ISSUE(s+2), MFMA(cur), acid(cur), fold, 1 barrier
    #define STAGE(s, ASc, BSc, BTc, ASn, BSn, BTn)                                  \
        {                                                                           \
            const int k0c_ = (s) * BK;                                              \
            bf16x8 af0 = *(const bf16x8*)(Ab +                                      \
                (size_t)(bm0 + wv * 32 + r16) * NIN + k0c_ + g * 8);                \
            bf16x8 af1 = *(const bf16x8*)(Ab +                                      \
                (size_t)(bm0 + wv * 32 + 16 + r16) * NIN + k0c_ + g * 8);           \
            if ((s) + 1 < NSTAGE) WRITE_LDS(ASn, BSn, BTn);                         \
            if ((s) + 2 < NSTAGE) ISSUE_LOADS((s) + 2);                             \
            _Pragma("unroll")                                                       \
            for (int tc = 0; tc < 8; ++tc) {                                        \
                int row_ = tc * 16 + r16;                                           \
                int cs_ = g ^ (row_ & 3);                                           \
                bf16x8 bf = *(const bf16x8*)&(BTc)[row_ * 32 + cs_ * 8];            \
                acc[0][tc] = __builtin_amdgcn_mfma_f32_16x16x32_bf16(af0, bf, acc[0][tc], 0, 0, 0);\
                acc[1][tc] = __builtin_amdgcn_mfma_f32_16x16x32_bf16(af1, bf, acc[1][tc], 0, 0, 0);\
            }                                                                       \
            _Pragma("unroll 4")                                                     \
            for (int k = 0; k < BK; ++k) {                                          \
                const float4 pa = *(const float4*)&(ASc)[k * 128 + ty * 8];         \
                const float4 pb = *(const float4*)&(ASc)[k * 128 + ty * 8 + 4];     \
                const float4 s0 = *(const float4*)&(BSc)[k * 128 + tx * 4];         \
                const float4 s1 = *(const float4*)&(BSc)[k * 128 + 64 + tx * 4];    \
                const float av[8] = {pa.x, pa.y, pa.z, pa.w, pb.x, pb.y, pb.z, pb.w};\
                const float sn[8] = {s0.x, s0.y, s0.z, s0.w, s1.x, s1.y, s1.z, s1.w};\
                _Pragma("unroll")                                                   \
                for (int m = 0; m < 8; ++m)                                         \
                    _Pragma("unroll")                                               \
                    for (int n = 0; n < 8; ++n)                                     \
                        ca[m][n] = fmaf(av[m], sn[n], ca[m][n]);                    \
            }                                                                       \
            if ((((s) + 1) & 15) == 0) {                                            \
                _Pragma("unroll")                                                   \
                for (int m = 0; m < 8; ++m)                                         \
                    _Pragma("unroll")                                               \
                    for (int n = 0; n < 8; ++n) {                                   \
                        ma[m][n] += ca[m][n]; ca[m][n] = 0.f;                       \
                    }                                                               \
            }                                                                       \
            __syncthreads();                                                        \
        }

    // prologue: stage 0 into buf0; stage 1 loads in flight
    ISSUE_LOADS(0);
    WRITE_LDS(As0, Bs0, Bt0);
    ISSUE_LOADS(1);
    __syncthreads();

    for (int s2 = 0; s2 < NSTAGE / 2; ++s2) {
        STAGE(2 * s2,     As0, Bs0, Bt0, As1, Bs1, Bt1);
        STAGE(2 * s2 + 1, As1, Bs1, Bt1, As0, Bs0, Bt0);
    }

    // ---- combine base frags + epilogue, two column halves (R15-verified) ----
    #pragma unroll
    for (int hh = 0; hh < 2; ++hh) {
        #pragma unroll
        for (int tr = 0; tr < 2; ++tr)
            #pragma unroll
            for (int tc = 0; tc < 4; ++tc)
                #pragma unroll
                for (int rr = 0; rr < 4; ++rr)
                    BoutH[(wv * 32 + tr * 16 + g * 4 + rr) * 68 + tc * 16 + r16] =
                        acc[tr][hh * 4 + tc][rr];
        __syncthreads();
        #pragma unroll
        for (int m = 0; m < 8; ++m) {
            int row = ty * 8 + m;
            const float4 bv = *(const float4*)&BoutH[row * 68 + tx * 4];
            const float bb[4] = {bv.x, bv.y, bv.z, bv.w};
            #pragma unroll
            for (int n = 0; n < 4; ++n) {
                float r    = ma[m][hh * 4 + n] - bb[n];
                float conc = fabsf(r) / 409.6f;
                float hc   = (r < 0.f) ? (1e-14f / conc) : conc;
                float ph   = (-logf(hc)) / 2.302585092994046f;
                out[(size_t)(bm0 + row) * NOUT + bn0 + hh * 64 + tx * 4 + n] = ph;
            }
        }
        __syncthreads();
    }
    #undef ISSUE_LOADS
    #undef WRITE_LDS
    #undef STAGE
}

// Fallback (ws too small): R9's proven all-VALU kernel, on-the-fly terms.
__global__ __launch_bounds__(256, 2) void acid_gemm_fly(const float* __restrict__ X,
                                                        const float* __restrict__ W,
                                                        float* __restrict__ out) {
    __shared__ float2 Asf[BK][128 + 2];
    __shared__ float  Bsf[BK][64];
    const int tid = threadIdx.x;
    const int tx = tid & 15, ty = tid >> 4;
    const int bm0 = blockIdx.y * 128, bn0 = blockIdx.x * 64;
    float ma[8][4] = {}, mb[8][4] = {}, ca[8][4] = {}, cb[8][4] = {};
    for (int s = 0; s < NSTAGE; ++s) {
        const int k0 = s * BK;
        for (int idx = tid; idx < 128 * BK; idx += 256) {
            int m = idx >> 5, k = idx & 31;
            Asf[k][m] = compute_terms(X[(size_t)(bm0 + m) * NIN + k0 + k]);
        }
        for (int idx = tid; idx < BK * 64; idx += 256) {
            int k = idx >> 6, c = idx & 63;
            Bsf[k][c] = signf_of(W[(size_t)(k0 + k) * NOUT + bn0 + c]);
        }
        __syncthreads();
        #pragma unroll 4
        for (int k = 0; k < BK; ++k) {
            float2 av[8]; float sv[4];
            #pragma unroll
            for (int m = 0; m < 8; ++m) av[m] = Asf[k][ty * 8 + m];
            #pragma unroll
            for (int n = 0; n < 4; ++n) sv[n] = Bsf[k][tx * 4 + n];
            #pragma unroll
            for (int m = 0; m < 8; ++m)
                #pragma unroll
                for (int n = 0; n < 4; ++n) {
                    ca[m][n] = fmaf(av[m].x, sv[n], ca[m][n]);
                    cb[m][n] = fmaf(av[m].y, sv[n], cb[m][n]);
                }
        }
        if (((s + 1) & 15) == 0) {
            #pragma unroll
            for (int m = 0; m < 8; ++m)
                #pragma unroll
                for (int n = 0; n < 4; ++n) {
                    ma[m][n] += ca[m][n]; ca[m][n] = 0.f;
                    mb[m][n] += cb[m][n]; cb[m][n] = 0.f;
                }
        }
        __syncthreads();
    }
    #pragma unroll
    for (int m = 0; m < 8; ++m) {
        int row = bm0 + ty * 8 + m;
        #pragma unroll
        for (int n = 0; n < 4; ++n) {
            int col = bn0 + tx * 4 + n;
            float r = ma[m][n] - mb[m][n];
            float conc = fabsf(r) / 409.6f;
            float hc = (r < 0.f) ? (1e-14f / conc) : conc;
            out[(size_t)row * NOUT + col] = (-logf(hc)) / 2.302585092994046f;
        }
    }
}

extern "C" void kernel_launch(void* const* d_in, const int* in_sizes, int n_in,
                              void* d_out, int out_size, void* d_ws, size_t ws_size,
                              hipStream_t stream) {
    const float* x = (const float*)d_in[0];
    const float* w = (const float*)d_in[1];
    float* out = (float*)d_out;

    const size_t nElem  = (size_t)BATCH * NIN;
    const size_t needWs = nElem * 4 + nElem * 2 + nElem * 2;   // AaT + Ab + signT = 134.2 MB
    dim3 grid(NOUT / BN, BATCH / BM);

    if (ws_size >= needWs) {
        float*          aaT   = (float*)d_ws;
        unsigned short* ab    = (unsigned short*)((char*)d_ws + nElem * 4);
        unsigned short* signT = (unsigned short*)((char*)d_ws + nElem * 6);
        precompute_A    <<<dim3(64, 64), 256, 0, stream>>>(x, aaT, ab);
        precompute_signT<<<dim3(64, 64), 256, 0, stream>>>(w, signT);
        acid_gemm_hyb   <<<grid, dim3(256), 0, stream>>>(aaT, ab, signT, w, out);
    } else {
        acid_gemm_fly<<<dim3(NOUT / 64, BATCH / 128), dim3(256), 0, stream>>>(x, w, out);
    }
}